// Round 4
// baseline (574.322 us; speedup 1.0000x reference)
//
#include <hip/hip_runtime.h>
#include <hip/hip_bf16.h>

// DF11Embedding forward: out[b,s,:] = weight[input_ids[b,s], :]
// input_ids: [8,4096] int32 (32768), weight: [50257,2048] f32, out: [8,4096,2048] f32.
// Pure gather, memory-bound. One float4 per thread; 512 float4 per row.

#define ROW_F4 512                 // 2048 floats / 4
#define ROW_SHIFT 9                // log2(512)

__global__ __launch_bounds__(256) void embed_gather_kernel(
    const int* __restrict__ ids,
    const float4* __restrict__ weight,   // [VOCAB][512] float4
    float4* __restrict__ out,            // [NTOK][512] float4
    int total_f4)                        // NTOK * 512
{
    int gid = blockIdx.x * blockDim.x + threadIdx.x;
    if (gid >= total_f4) return;
    int token = gid >> ROW_SHIFT;
    int col   = gid & (ROW_F4 - 1);
    int row   = ids[token];
    out[gid] = weight[(long long)row * ROW_F4 + col];
}

extern "C" void kernel_launch(void* const* d_in, const int* in_sizes, int n_in,
                              void* d_out, int out_size, void* d_ws, size_t ws_size,
                              hipStream_t stream) {
    const int*    ids    = (const int*)d_in[0];     // [8*4096]
    const float4* weight = (const float4*)d_in[1];  // [50257*512] as float4
    float4*       out    = (float4*)d_out;

    int ntok = in_sizes[0];                 // 32768
    int total_f4 = ntok * ROW_F4;           // 16,777,216
    int block = 256;
    int grid  = (total_f4 + block - 1) / block;  // 65536

    embed_gather_kernel<<<grid, block, 0, stream>>>(ids, weight, out, total_f4);
}

// Round 5
// 573.139 us; speedup vs baseline: 1.0021x; 1.0021x over previous
//
#include <hip/hip_runtime.h>
#include <hip/hip_bf16.h>

// DF11Embedding forward: out[b,s,:] = weight[input_ids[b,s], :]
// input_ids: [8,4096] int32 (32768), weight: [50257,2048] f32, out: [8,4096,2048] f32.
// Pure gather, memory-bound. 16 B/lane, nontemporal streaming stores (out has
// zero reuse; preserve L2/L3 for the ~197 MiB touched weight subset, which
// fits in the 256 MiB Infinity Cache across graph replays).

typedef float f32x4 __attribute__((ext_vector_type(4)));

#define ROW_F4 512                 // 2048 floats / 4
#define ROW_SHIFT 9                // log2(512)

__global__ __launch_bounds__(256) void embed_gather_kernel(
    const int* __restrict__ ids,
    const f32x4* __restrict__ weight,   // [VOCAB][512]
    f32x4* __restrict__ out,            // [NTOK][512]
    int total_f4)                       // NTOK * 512
{
    const int stride = gridDim.x * blockDim.x;
    int gid = blockIdx.x * blockDim.x + threadIdx.x;
    // A wave's 64 consecutive gids never straddle a 512-aligned row boundary
    // (64 | 512), so token — and the row id — is wave-uniform: scalarize it.
    #pragma unroll 4
    for (; gid < total_f4; gid += stride) {
        int token = gid >> ROW_SHIFT;
        int col   = gid & (ROW_F4 - 1);
        int row   = __builtin_amdgcn_readfirstlane(ids[token]);
        f32x4 v = weight[(size_t)row * ROW_F4 + col];
        __builtin_nontemporal_store(v, out + gid);
    }
}

extern "C" void kernel_launch(void* const* d_in, const int* in_sizes, int n_in,
                              void* d_out, int out_size, void* d_ws, size_t ws_size,
                              hipStream_t stream) {
    const int*   ids    = (const int*)d_in[0];     // [8*4096]
    const f32x4* weight = (const f32x4*)d_in[1];   // [50257*512]
    f32x4*       out    = (f32x4*)d_out;

    int ntok = in_sizes[0];                 // 32768
    int total_f4 = ntok * ROW_F4;           // 16,777,216

    int block = 256;
    int grid  = (total_f4 + block - 1) / block;
    if (grid > 2048) grid = 2048;           // grid-stride: 32 iters/thread

    embed_gather_kernel<<<grid, block, 0, stream>>>(ids, weight, out, total_f4);
}